// Round 14
// baseline (408.311 us; speedup 1.0000x reference)
//
#include <hip/hip_runtime.h>
#include <stdint.h>

// GraphConvLayer: out[n,:] = W[type[n]] @ (A @ x)[n,:]
// N=16384, D=128, T=8.  A is 1 GiB f32 read exactly once -> HBM floor ~163us.
// Round 14: A straight HBM->VGPR via pinned asm-volatile global_load_dwordx4
// (2-deep named-register parities; RA cannot sink/collapse asm) + manual
// counted vmcnt + sched_barrier(0) after each waitcnt (guide rule #18).
// X stays DMA->LDS (2 x 32KB). MFMA 32x32x16, 4 waves, wave tile 32x64.
// Per-phase LDS traffic 256KB -> 96KB; A's LDS round-trip eliminated.

#define N_NODES 16384
#define DIM     128
#define NTYPES  8
#define BM      64
#define BK      128
#define NT_K    (N_NODES / BK)   // 128 tiles

typedef float  f32x4  __attribute__((ext_vector_type(4)));
typedef float  f32x16 __attribute__((ext_vector_type(16)));
typedef __bf16 bf16x8 __attribute__((ext_vector_type(8)));

__device__ __attribute__((aligned(16))) unsigned short g_xT[DIM * N_NODES];      // [d][n], 4 MiB bf16
__device__ __attribute__((aligned(16))) unsigned short g_Wb[NTYPES * DIM * DIM]; // [t][o][d], 256 KiB

__device__ __forceinline__ unsigned int f2b(float f) {
    unsigned int u = __float_as_uint(f);
    u += 0x7FFFu + ((u >> 16) & 1u);   // round-to-nearest-even
    return u >> 16;
}
#define BF_LO(u) __uint_as_float((unsigned int)(u) << 16)
#define BF_HI(u) __uint_as_float((unsigned int)(u) & 0xFFFF0000u)

__device__ __forceinline__ bf16x8 cvt8(const f32x4 lo, const f32x4 hi) {
    bf16x8 r;
    r[0] = (__bf16)lo[0]; r[1] = (__bf16)lo[1]; r[2] = (__bf16)lo[2]; r[3] = (__bf16)lo[3];
    r[4] = (__bf16)hi[0]; r[5] = (__bf16)hi[1]; r[6] = (__bf16)hi[2]; r[7] = (__bf16)hi[3];
    return r;
}

// ---------------- fused prep kernel ----------------

__global__ void prep_all(const float* __restrict__ x, const float* __restrict__ w) {
    const int tid = threadIdx.x;
    if (blockIdx.x < 64) {
        int n = blockIdx.x * 256 + tid;
        const float* row = x + (size_t)n * DIM;
#pragma unroll
        for (int d0 = 0; d0 < DIM; d0 += 4) {
            float4 v = *(const float4*)(row + d0);
            g_xT[(d0 + 0) * N_NODES + n] = (unsigned short)f2b(v.x);
            g_xT[(d0 + 1) * N_NODES + n] = (unsigned short)f2b(v.y);
            g_xT[(d0 + 2) * N_NODES + n] = (unsigned short)f2b(v.z);
            g_xT[(d0 + 3) * N_NODES + n] = (unsigned short)f2b(v.w);
        }
    } else {
        int base = ((blockIdx.x - 64) * 256 + tid) * 16;
#pragma unroll
        for (int j = 0; j < 4; ++j) {
            float4 v = *(const float4*)(w + base + j * 4);
            ushort4 o;
            o.x = (unsigned short)f2b(v.x); o.y = (unsigned short)f2b(v.y);
            o.z = (unsigned short)f2b(v.z); o.w = (unsigned short)f2b(v.w);
            *(ushort4*)(g_Wb + base + j * 4) = o;
        }
    }
}

// ---------------- main fused kernel ----------------

#define XBYTES 32768   // X tile: 128 d-rows x 256B (16 x 16B chunks/row)

#define GLOAD16(g, l) __builtin_amdgcn_global_load_lds(                         \
    (const __attribute__((address_space(1))) unsigned int*)(g),                 \
    (__attribute__((address_space(3))) unsigned int*)(l), 16, 0, 0)

// pinned A load: asm volatile cannot be sunk/DCE'd; data ready after vmcnt
#define ALOAD(reg, ptr, off) \
    asm volatile("global_load_dwordx4 %0, %1, off offset:" #off : "=v"(reg) : "v"(ptr))

// issue one A tile (16 rows-of... per lane: 8 ksteps x 2 f32x4, contiguous 512B)
#define ISSUE_A(P, pa) do {                          \
    ALOAD(P##0,  pa,   0); ALOAD(P##1,  pa,  16);    \
    ALOAD(P##2,  pa,  64); ALOAD(P##3,  pa,  80);    \
    ALOAD(P##4,  pa, 128); ALOAD(P##5,  pa, 144);    \
    ALOAD(P##6,  pa, 192); ALOAD(P##7,  pa, 208);    \
    ALOAD(P##8,  pa, 256); ALOAD(P##9,  pa, 272);    \
    ALOAD(P##10, pa, 320); ALOAD(P##11, pa, 336);    \
    ALOAD(P##12, pa, 384); ALOAD(P##13, pa, 400);    \
    ALOAD(P##14, pa, 448); ALOAD(P##15, pa, 464);    \
    pa += 2 * BK;   /* this parity's next use is 2 tiles on */ \
} while (0)

// issue one X tile via DMA: 8 calls/wave, call j covers d-rows j*16+4w+(l>>4)
#define ISSUE_X(Xb) do {                                          \
    GLOAD16(gX0, (Xb) + 0 * 4096 + wq); gX0 += BK;                \
    GLOAD16(gX1, (Xb) + 1 * 4096 + wq); gX1 += BK;                \
    GLOAD16(gX2, (Xb) + 2 * 4096 + wq); gX2 += BK;                \
    GLOAD16(gX3, (Xb) + 3 * 4096 + wq); gX3 += BK;                \
    GLOAD16(gX4, (Xb) + 4 * 4096 + wq); gX4 += BK;                \
    GLOAD16(gX5, (Xb) + 5 * 4096 + wq); gX5 += BK;                \
    GLOAD16(gX6, (Xb) + 6 * 4096 + wq); gX6 += BK;                \
    GLOAD16(gX7, (Xb) + 7 * 4096 + wq); gX7 += BK;                \
} while (0)

// one k-substep (k=16): A cvt from 2 asm-loaded f32x4; 2 MFMA 32x32x16
#define KS(rE, rO, Xb, xk) do {                                                 \
    bf16x8 _a  = cvt8(rE, rO);                                                  \
    bf16x8 _b0 = *(const bf16x8*)((Xb) + xb0 + (xk));                           \
    bf16x8 _b1 = *(const bf16x8*)((Xb) + xb1 + (xk));                           \
    accA = __builtin_amdgcn_mfma_f32_32x32x16_bf16(_a, _b0, accA, 0, 0, 0);     \
    accB = __builtin_amdgcn_mfma_f32_32x32x16_bf16(_a, _b1, accB, 0, 0, 0);     \
} while (0)

#define COMPUTE(P, Xb) do {                  \
    KS(P##0,  P##1,  Xb, xk0);               \
    KS(P##2,  P##3,  Xb, xk1);               \
    KS(P##4,  P##5,  Xb, xk2);               \
    KS(P##6,  P##7,  Xb, xk3);               \
    KS(P##8,  P##9,  Xb, xk4);               \
    KS(P##10, P##11, Xb, xk5);               \
    KS(P##12, P##13, Xb, xk6);               \
    KS(P##14, P##15, Xb, xk7);               \
} while (0)

// counted wait + scheduler fence (rule #18: MFMA/VALU would be hoisted past
// an inline-asm waitcnt otherwise)
#define WAITV(N) do {                                            \
    asm volatile("s_waitcnt vmcnt(" #N ")" ::: "memory");        \
    __builtin_amdgcn_sched_barrier(0);                           \
} while (0)

__global__ __launch_bounds__(256, 1) void gconv_main(
    const float* __restrict__ adj,
    const int* __restrict__ types,
    float* __restrict__ out)
{
    __shared__ __align__(16) unsigned char lds[2 * XBYTES];   // 65536 B (agg reuse)
    unsigned char* Xb0 = lds;
    unsigned char* Xb1 = lds + XBYTES;

    const int tid  = threadIdx.x;
    const int w    = tid >> 6;          // 0..3
    const int l    = tid & 63;
    const int m0   = blockIdx.x * BM;

    const int mrow = (w & 1) * 32;      // wave tile: 32 rows x 64 cols
    const int ncol = (w >> 1) * 64;

    f32x16 accA = {}, accB = {};

    // ---- A per-lane pointer: row = m0+mrow+(l&31), k-half (l>>5)*8 floats.
    // Per kstep kc the two 16B loads sit at kc*64 and kc*64+16 (imm offsets).
    const float* aBase = adj + (size_t)(m0 + mrow + (l & 31)) * N_NODES + ((l >> 5) << 3);
    const float* pa0 = aBase;            // even-parity tiles
    const float* pa1 = aBase + BK;       // odd-parity tiles

    // ---- X DMA source pointers (pre-swizzled; linear LDS dest, m173/T2).
    // call j: d = j*16 + 4w + (l>>4); phys chunk l&15 <- logical (l&15)^(d&7)
    const int xr = 4 * w + (l >> 4);
    const unsigned short* gX0 = g_xT + (size_t)(  0 + xr) * N_NODES + (((l & 15) ^ (xr & 7)) << 3);
    const unsigned short* gX1 = g_xT + (size_t)( 16 + xr) * N_NODES + (((l & 15) ^ (xr & 7)) << 3);
    const unsigned short* gX2 = g_xT + (size_t)( 32 + xr) * N_NODES + (((l & 15) ^ (xr & 7)) << 3);
    const unsigned short* gX3 = g_xT + (size_t)( 48 + xr) * N_NODES + (((l & 15) ^ (xr & 7)) << 3);
    const unsigned short* gX4 = g_xT + (size_t)( 64 + xr) * N_NODES + (((l & 15) ^ (xr & 7)) << 3);
    const unsigned short* gX5 = g_xT + (size_t)( 80 + xr) * N_NODES + (((l & 15) ^ (xr & 7)) << 3);
    const unsigned short* gX6 = g_xT + (size_t)( 96 + xr) * N_NODES + (((l & 15) ^ (xr & 7)) << 3);
    const unsigned short* gX7 = g_xT + (size_t)(112 + xr) * N_NODES + (((l & 15) ^ (xr & 7)) << 3);
    const int wq = w << 10;             // wave's 1KB slot within each 4KB call round

    // ---- X read offsets: d = ncol + nt*32 + (l&31), d&7 = l&7;
    // logical chunk kc*2+(l>>5), phys = logical ^ (l&7).
    const int h  = l >> 5;
    const int e  = l & 7;
    const int xb0 = (ncol +  0 + (l & 31)) * 256;
    const int xb1 = (ncol + 32 + (l & 31)) * 256;
    const int xk0 = (( 0 + h) ^ e) << 4;
    const int xk1 = (( 2 + h) ^ e) << 4;
    const int xk2 = (( 4 + h) ^ e) << 4;
    const int xk3 = (( 6 + h) ^ e) << 4;
    const int xk4 = (( 8 + h) ^ e) << 4;
    const int xk5 = ((10 + h) ^ e) << 4;
    const int xk6 = ((12 + h) ^ e) << 4;
    const int xk7 = ((14 + h) ^ e) << 4;

    // ---- named A register parities (asm outputs; RA must keep them) ----
    f32x4 p0, p1, p2, p3, p4, p5, p6, p7, p8, p9, p10, p11, p12, p13, p14, p15;
    f32x4 q0, q1, q2, q3, q4, q5, q6, q7, q8, q9, q10, q11, q12, q13, q14, q15;

    // ---- prologue: tiles 0,1 in flight (48 VMEM ops/wave outstanding) ----
    ISSUE_A(p, pa0); ISSUE_X(Xb0);      // tile 0
    ISSUE_A(q, pa1); ISSUE_X(Xb1);      // tile 1

    // ---- 128 phases; phases 0..125 issue tile t+2 ----
    for (int i = 0; i < 63; ++i) {
        // even phase: compute parity 0, issue same parity (t+2)
        WAITV(24);
        __builtin_amdgcn_s_barrier();
        COMPUTE(p, Xb0);
        __builtin_amdgcn_sched_barrier(0);
        __builtin_amdgcn_s_barrier();
        ISSUE_A(p, pa0); ISSUE_X(Xb0);
        // odd phase
        WAITV(24);
        __builtin_amdgcn_s_barrier();
        COMPUTE(q, Xb1);
        __builtin_amdgcn_sched_barrier(0);
        __builtin_amdgcn_s_barrier();
        ISSUE_A(q, pa1); ISSUE_X(Xb1);
    }
    WAITV(24);                           // t=126 (127's 24 ops still in flight)
    __builtin_amdgcn_s_barrier();
    COMPUTE(p, Xb0);
    WAITV(0);                            // t=127
    __builtin_amdgcn_s_barrier();
    COMPUTE(q, Xb1);
    __syncthreads();                     // drain before reusing LDS as agg

    // ---- epilogue: acc -> LDS agg (f32), then per-row W[type] dots ----
    // 32x32 C/D layout (m74/m101): col = lane&31, row = (reg&3)+8*(reg>>2)+4*(lane>>5)
    float* agg = (float*)lds;   // [64][132] = 33792 B
#pragma unroll
    for (int rg = 0; rg < 16; ++rg) {
        const int row = mrow + (rg & 3) + 8 * (rg >> 2) + 4 * (l >> 5);
        agg[row * 132 + ncol +  0 + (l & 31)] = accA[rg];
        agg[row * 132 + ncol + 32 + (l & 31)] = accB[rg];
    }
    __syncthreads();

    const int rbase = w * 16;   // 16 rows per wave (4 waves)
    for (int rr = 0; rr < 16; ++rr) {
        const int rw = rbase + rr;
        const int nn = m0 + rw;
        const int ty = types[nn];                      // wave-uniform
        const unsigned short* Wt = g_Wb + ty * (DIM * DIM);
        const int o0 = l * 2;
        const float* aggRow = agg + rw * 132;
        float s0 = 0.f, s1 = 0.f;
#pragma unroll
        for (int d0 = 0; d0 < DIM; d0 += 8) {
            float4 ga = *(const float4*)(aggRow + d0);
            float4 gb = *(const float4*)(aggRow + d0 + 4);
            uint4 wa = *(const uint4*)(Wt + o0 * DIM + d0);
            uint4 wb = *(const uint4*)(Wt + (o0 + 1) * DIM + d0);
            s0 += ga.x * BF_LO(wa.x) + ga.y * BF_HI(wa.x) + ga.z * BF_LO(wa.y) + ga.w * BF_HI(wa.y);
            s0 += gb.x * BF_LO(wa.z) + gb.y * BF_HI(wa.z) + gb.z * BF_LO(wa.w) + gb.w * BF_HI(wa.w);
            s1 += ga.x * BF_LO(wb.x) + ga.y * BF_HI(wb.x) + ga.z * BF_LO(wb.y) + ga.w * BF_HI(wb.y);
            s1 += gb.x * BF_LO(wb.z) + gb.y * BF_HI(wb.z) + gb.z * BF_LO(wb.w) + gb.w * BF_HI(wb.w);
        }
        float2 res; res.x = s0; res.y = s1;
        *(float2*)(out + (size_t)nn * DIM + o0) = res;
    }
}

// ---------------- launch ----------------

extern "C" void kernel_launch(void* const* d_in, const int* in_sizes, int n_in,
                              void* d_out, int out_size, void* d_ws, size_t ws_size,
                              hipStream_t stream) {
    const float* x     = (const float*)d_in[0];
    const int*   types = (const int*)d_in[1];
    const float* adj   = (const float*)d_in[2];
    const float* wt    = (const float*)d_in[3];
    float* out = (float*)d_out;

    hipLaunchKernelGGL(prep_all, dim3(96), dim3(256), 0, stream, x, wt);
    hipLaunchKernelGGL(gconv_main, dim3(N_NODES / BM), dim3(256), 0, stream, adj, types, out);
}